// Round 1
// baseline (237.186 us; speedup 1.0000x reference)
//
#include <hip/hip_runtime.h>
#include <math.h>

// ---------------------------------------------------------------------------
// 9-qubit batched state-vector simulator.
// One wave (64 lanes) per batch element; 8 complex amps per lane in registers.
// i = lane*8 + k ; qubit w <-> index bit (8-w).
//   qubits 0..5  -> lane bits 5..0  (cross-lane gates via shfl_xor)
//   qubits 6..8  -> k bits 2..0     (in-register gates)
// CNOT ring layers are compile-time-known permutations (RANGES = 1,2,3),
// applied via an LDS scatter/gather with a baked constexpr table.
// ---------------------------------------------------------------------------

struct PermTables { unsigned short t[3][512]; };

constexpr PermTables make_perm() {
    PermTables p{};
    for (int l = 0; l < 3; ++l) {
        const int r = l + 1;
        for (int i = 0; i < 512; ++i) {
            int j = i;
            for (int c = 0; c < 9; ++c) {
                const int bit = (j >> (8 - c)) & 1;
                const int t = (c + r) % 9;
                j ^= bit << (8 - t);
            }
            p.t[l][i] = (unsigned short)j;
        }
    }
    return p;
}

__device__ const PermTables PERM = make_perm();

__global__ __launch_bounds__(64) void qsim_kernel(
        const float* __restrict__ x,       // (batch, 9)
        const float* __restrict__ wt,      // (3, 9, 3)
        float* __restrict__ out,           // (batch, 9)
        int batch) {
    __shared__ float  gmat[27 * 8];        // 27 gates * (m00,m01,m10,m11) complex
    __shared__ float2 st[512];             // permutation staging buffer

    const int b    = blockIdx.x;
    const int lane = threadIdx.x;          // 0..63, one wave

    // ---- rotation matrices (uniform across batch): lanes 0..26 build them ----
    if (lane < 27) {
        const float phi = wt[lane * 3 + 0];
        const float th  = wt[lane * 3 + 1];
        const float om  = wt[lane * 3 + 2];
        float s, c;   __sincosf(0.5f * th, &s, &c);
        float sa, ca; __sincosf(0.5f * (phi + om), &sa, &ca);
        float sb, cb; __sincosf(0.5f * (phi - om), &sb, &cb);
        float* o = &gmat[lane * 8];
        o[0] =  ca * c;  o[1] = -sa * c;   // m00 = e^{-i(phi+om)/2} cos
        o[2] = -cb * s;  o[3] = -sb * s;   // m01 = -e^{+i(phi-om)/2} sin
        o[4] =  cb * s;  o[5] = -sb * s;   // m10 = e^{-i(phi-om)/2} sin
        o[6] =  ca * c;  o[7] =  sa * c;   // m11 = e^{+i(phi+om)/2} cos
    }
    __syncthreads();

    if (b >= batch) return;

    // ---- initial product state: s_i = (prod cos/sin) * (-i)^popcount(i) ----
    float cx[9], sx[9];
    #pragma unroll
    for (int w = 0; w < 9; ++w) {
        const float h = 0.5f * x[b * 9 + w];
        __sincosf(h, &sx[w], &cx[w]);
    }

    float P = 1.0f;
    #pragma unroll
    for (int w = 0; w < 6; ++w)
        P *= ((lane >> (5 - w)) & 1) ? sx[w] : cx[w];

    float re[8], im[8];
    #pragma unroll
    for (int k = 0; k < 8; ++k) {
        float m = P * ((k & 4) ? sx[6] : cx[6])
                    * ((k & 2) ? sx[7] : cx[7])
                    * ((k & 1) ? sx[8] : cx[8]);
        const int i  = (lane << 3) | k;
        const int pc = __popc(i) & 3;      // (-i)^pc : 1, -i, -1, +i
        re[k] = (pc == 0) ? m : ((pc == 2) ? -m : 0.0f);
        im[k] = (pc == 1) ? -m : ((pc == 3) ? m : 0.0f);
    }

    // ---- 3 layers: 9 rotations + CNOT ring permutation ----
    for (int l = 0; l < 3; ++l) {
        #pragma unroll
        for (int w = 0; w < 9; ++w) {
            const float* gm = &gmat[(l * 9 + w) * 8];
            const float m00r = gm[0], m00i = gm[1];
            const float m01r = gm[2], m01i = gm[3];
            const float m10r = gm[4], m10i = gm[5];
            const float m11r = gm[6], m11i = gm[7];

            if (w < 6) {
                // cross-lane gate: partner lane differs in bit (5-w)
                const int  mask = 1 << (5 - w);
                const bool hi   = (lane >> (5 - w)) & 1;
                // my new amp = c_a * mine + c_b * partner
                const float car = hi ? m11r : m00r;
                const float cai = hi ? m11i : m00i;
                const float cbr = hi ? m10r : m01r;
                const float cbi = hi ? m10i : m01i;
                #pragma unroll
                for (int k = 0; k < 8; ++k) {
                    const float pr = __shfl_xor(re[k], mask, 64);
                    const float pi = __shfl_xor(im[k], mask, 64);
                    const float nr = car * re[k] - cai * im[k] + cbr * pr - cbi * pi;
                    const float ni = car * im[k] + cai * re[k] + cbr * pi + cbi * pr;
                    re[k] = nr; im[k] = ni;
                }
            } else {
                // in-register gate on k-bit (8-w): 4 disjoint pairs
                const int kb = 1 << (8 - w);     // 4, 2, 1
                #pragma unroll
                for (int k0 = 0; k0 < 8; ++k0) {
                    if (k0 & kb) continue;
                    const int k1 = k0 | kb;
                    const float a0r = re[k0], a0i = im[k0];
                    const float a1r = re[k1], a1i = im[k1];
                    re[k0] = m00r * a0r - m00i * a0i + m01r * a1r - m01i * a1i;
                    im[k0] = m00r * a0i + m00i * a0r + m01r * a1i + m01i * a1r;
                    re[k1] = m10r * a0r - m10i * a0i + m11r * a1r - m11i * a1i;
                    im[k1] = m10r * a0i + m10i * a0r + m11r * a1i + m11i * a1r;
                }
            }
        }

        // CNOT ring: psi_new[perm(i)] = psi_old[i]  (scatter, then gather back)
        __syncthreads();   // protect previous layer's LDS reads
        #pragma unroll
        for (int k = 0; k < 8; ++k) {
            const int j = PERM.t[l][(lane << 3) | k];
            st[j] = make_float2(re[k], im[k]);
        }
        __syncthreads();
        #pragma unroll
        for (int k = 0; k < 8; ++k) {
            const float2 v = st[(lane << 3) | k];
            re[k] = v.x; im[k] = v.y;
        }
    }

    // ---- epilogue: probs -> 9 Z-expectations ----
    float p[8];
    #pragma unroll
    for (int k = 0; k < 8; ++k) p[k] = re[k] * re[k] + im[k] * im[k];

    float S = 0.0f;
    #pragma unroll
    for (int k = 0; k < 8; ++k) S += p[k];

    float c[9];
    #pragma unroll
    for (int w = 0; w < 6; ++w)
        c[w] = ((lane >> (5 - w)) & 1) ? -S : S;
    c[6] = 0.0f; c[7] = 0.0f; c[8] = 0.0f;
    #pragma unroll
    for (int k = 0; k < 8; ++k) {
        c[6] += (k & 4) ? -p[k] : p[k];
        c[7] += (k & 2) ? -p[k] : p[k];
        c[8] += (k & 1) ? -p[k] : p[k];
    }

    // wave-wide butterfly reduction of the 9 sums
    #pragma unroll
    for (int d = 1; d < 64; d <<= 1) {
        #pragma unroll
        for (int w = 0; w < 9; ++w)
            c[w] += __shfl_xor(c[w], d, 64);
    }

    // lane w stores c[w] (w < 9)
    float v = c[0];
    #pragma unroll
    for (int w = 1; w < 9; ++w)
        v = (lane == w) ? c[w] : v;
    if (lane < 9)
        out[b * 9 + lane] = v;
}

extern "C" void kernel_launch(void* const* d_in, const int* in_sizes, int n_in,
                              void* d_out, int out_size, void* d_ws, size_t ws_size,
                              hipStream_t stream) {
    const float* x  = (const float*)d_in[0];   // (32768, 9) fp32
    const float* wt = (const float*)d_in[1];   // (3, 9, 3) fp32
    float* out = (float*)d_out;                // (32768, 9) fp32
    const int batch = in_sizes[0] / 9;

    hipLaunchKernelGGL(qsim_kernel, dim3(batch), dim3(64), 0, stream,
                       x, wt, out, batch);
}

// Round 2
// 161.086 us; speedup vs baseline: 1.4724x; 1.4724x over previous
//
#include <hip/hip_runtime.h>

// ---------------------------------------------------------------------------
// 9-qubit batched state-vector simulator, v2.
// One wave per batch element, 4 waves (4 batch elems) per 256-thread block.
// All 27 rotation gates applied IN-REGISTER by cycling three layouts per
// layer (single-qubit rotations commute):
//   layout A: reg bits = qubits 6,7,8   (i = L<<3 | k)
//   layout B: reg bits = qubits 3,4,5   (i = (L&0x38)<<3 | k<<3 | (L&7))
//   layout C: reg bits = qubits 0,1,2   (i = k<<6 | L)
// Transitions via per-wave LDS float2[512] with linear swizzle
// sigma(i) = i ^ (i>>4)  -> all round-trips are bank-conflict-free
// (rank-4 bank-pair maps, verified by GF(2) analysis for all 3 CNOT layers).
// The CNOT ring permutation (compile-time-known GF(2)-linear map) is folded
// into the C->A transition's write addresses as baked XOR constants.
// No __syncthreads anywhere: per-wave LDS buffers + same-wave DS ordering.
// ---------------------------------------------------------------------------

constexpr int pf(int l, int i) {        // forward CNOT-ring basis map, layer l
    const int r = l + 1; int j = i;
    for (int c = 0; c < 9; ++c) {
        const int bit = (j >> (8 - c)) & 1;
        const int t = (c + r) % 9;
        j ^= bit << (8 - t);
    }
    return j;
}
constexpr int sg(int i) { return i ^ (i >> 4); }   // LDS anti-conflict swizzle

struct T3Tab {
    int laneBase[3][6];   // sg(pf(l, 1<<b))  — lane-bit basis images
    int regPart [3][8];   // sg(pf(l, g<<6))  — reg-part images (layout C)
};
constexpr T3Tab make_t3() {
    T3Tab t{};
    for (int l = 0; l < 3; ++l) {
        for (int b = 0; b < 6; ++b) t.laneBase[l][b] = sg(pf(l, 1 << b));
        for (int g = 0; g < 8; ++g) t.regPart [l][g] = sg(pf(l, g << 6));
    }
    return t;
}
constexpr T3Tab T3T = make_t3();

// sg(k<<3) and sg(k<<6) as constexpr helpers (compile-time at unrolled sites)
constexpr int sgk3(int k) { return (k << 3) ^ (k >> 1); }
constexpr int sgk6(int k) { return (k << 6) ^ (k << 2); }

#define APPLY_GATE(gidx, KB)                                                  \
    {                                                                         \
        const float4 g0 = G[(gidx)*2], g1 = G[(gidx)*2+1];                    \
        _Pragma("unroll")                                                     \
        for (int k0 = 0; k0 < 8; ++k0) if (!(k0 & (KB))) {                    \
            const int k1 = k0 | (KB);                                         \
            const float a0r = re[k0], a0i = im[k0];                           \
            const float a1r = re[k1], a1i = im[k1];                           \
            re[k0] = g0.x*a0r - g0.y*a0i + g0.z*a1r - g0.w*a1i;               \
            im[k0] = g0.x*a0i + g0.y*a0r + g0.z*a1i + g0.w*a1r;               \
            re[k1] = g1.x*a0r - g1.y*a0i + g1.z*a1r - g1.w*a1i;               \
            im[k1] = g1.x*a0i + g1.y*a0r + g1.z*a1i + g1.w*a1r;               \
        }                                                                     \
    }

__global__ __launch_bounds__(256) void qsim_kernel(
        const float* __restrict__ x,       // (batch, 9)
        const float* __restrict__ wt,      // (3, 9, 3)
        float* __restrict__ out,           // (batch, 9)
        int batch) {
    __shared__ float2 st[4][512];          // per-wave staging (16 KiB)
    __shared__ float4 gm[4][27 * 2];       // per-wave gate matrices (3.4 KiB)

    const int tid  = threadIdx.x;
    const int wv   = tid >> 6;
    const int lane = tid & 63;
    const int b    = blockIdx.x * 4 + wv;

    // ---- per-wave rotation matrices: lanes 0..26 build them (no barrier) ----
    if (lane < 27) {
        const float phi = wt[lane * 3 + 0];
        const float th  = wt[lane * 3 + 1];
        const float om  = wt[lane * 3 + 2];
        float s, c;   __sincosf(0.5f * th, &s, &c);
        float sa, ca; __sincosf(0.5f * (phi + om), &sa, &ca);
        float sb, cb; __sincosf(0.5f * (phi - om), &sb, &cb);
        gm[wv][lane * 2 + 0] = make_float4(ca * c, -sa * c, -cb * s, -sb * s); // m00, m01
        gm[wv][lane * 2 + 1] = make_float4(cb * s, -sb * s,  ca * c,  sa * c); // m10, m11
    }

    if (b >= batch) return;

    float2* __restrict__ S = st[wv];
    const float4* __restrict__ G = gm[wv];

    // ---- initial product state: s_i = (prod cos/sin) * (-i)^popcount(i) ----
    float cx[9], sx[9];
    #pragma unroll
    for (int w = 0; w < 9; ++w) {
        const float h = 0.5f * x[b * 9 + w];
        __sincosf(h, &sx[w], &cx[w]);
    }

    float P = 1.0f;
    #pragma unroll
    for (int w = 0; w < 6; ++w)
        P *= ((lane >> (5 - w)) & 1) ? sx[w] : cx[w];

    float re[8], im[8];
    #pragma unroll
    for (int k = 0; k < 8; ++k) {
        float m = P * ((k & 4) ? sx[6] : cx[6])
                    * ((k & 2) ? sx[7] : cx[7])
                    * ((k & 1) ? sx[8] : cx[8]);
        const int i  = (lane << 3) | k;
        const int pc = __popc(i) & 3;      // (-i)^pc : 1, -i, -1, +i
        re[k] = (pc == 0) ? m : ((pc == 2) ? -m : 0.0f);
        im[k] = (pc == 1) ? -m : ((pc == 3) ? m : 0.0f);
    }

    // ---- lane-dependent swizzled address bases ----
    const int baseA = (lane << 3) ^ (lane >> 1);            // sg(L<<3)
    const int hB    = ((lane & 0x38) << 3) | (lane & 7);
    const int baseB = hB ^ (hB >> 4);                       // sg(layB(L,0))
    const int baseC = lane ^ (lane >> 4);                   // sg(L)
    int t3b[3];
    #pragma unroll
    for (int l = 0; l < 3; ++l) {
        int v = 0;
        #pragma unroll
        for (int bb = 0; bb < 6; ++bb)
            v ^= ((lane >> bb) & 1) ? T3T.laneBase[l][bb] : 0;
        t3b[l] = v;                                         // sg(pf(l, L))
    }

    // ---- 3 layers: 9 in-register gates + 3 swizzled LDS transitions ----
    #pragma unroll
    for (int l = 0; l < 3; ++l) {
        // qubits 6,7,8 (layout A: reg bits 2,1,0)
        APPLY_GATE(l * 9 + 6, 4);
        APPLY_GATE(l * 9 + 7, 2);
        APPLY_GATE(l * 9 + 8, 1);

        // T1: A -> B
        #pragma unroll
        for (int k = 0; k < 8; ++k) S[baseA ^ k] = make_float2(re[k], im[k]);
        #pragma unroll
        for (int k = 0; k < 8; ++k) {
            const float2 v = S[baseB ^ sgk3(k)];
            re[k] = v.x; im[k] = v.y;
        }

        // qubits 3,4,5 (layout B)
        APPLY_GATE(l * 9 + 3, 4);
        APPLY_GATE(l * 9 + 4, 2);
        APPLY_GATE(l * 9 + 5, 1);

        // T2: B -> C
        #pragma unroll
        for (int k = 0; k < 8; ++k) S[baseB ^ sgk3(k)] = make_float2(re[k], im[k]);
        #pragma unroll
        for (int k = 0; k < 8; ++k) {
            const float2 v = S[baseC ^ sgk6(k)];
            re[k] = v.x; im[k] = v.y;
        }

        // qubits 0,1,2 (layout C)
        APPLY_GATE(l * 9 + 0, 4);
        APPLY_GATE(l * 9 + 1, 2);
        APPLY_GATE(l * 9 + 2, 1);

        // T3: C -> A with the layer's CNOT-ring permutation folded in
        #pragma unroll
        for (int k = 0; k < 8; ++k) S[t3b[l] ^ T3T.regPart[l][k]] = make_float2(re[k], im[k]);
        #pragma unroll
        for (int k = 0; k < 8; ++k) {
            const float2 v = S[baseA ^ k];
            re[k] = v.x; im[k] = v.y;
        }
    }

    // ---- epilogue: probs -> 9 Z-expectations ----
    float p[8];
    #pragma unroll
    for (int k = 0; k < 8; ++k) p[k] = re[k] * re[k] + im[k] * im[k];

    float Sm = 0.0f;
    #pragma unroll
    for (int k = 0; k < 8; ++k) Sm += p[k];

    float c[9];
    #pragma unroll
    for (int w = 0; w < 6; ++w)
        c[w] = ((lane >> (5 - w)) & 1) ? -Sm : Sm;
    c[6] = 0.0f; c[7] = 0.0f; c[8] = 0.0f;
    #pragma unroll
    for (int k = 0; k < 8; ++k) {
        c[6] += (k & 4) ? -p[k] : p[k];
        c[7] += (k & 2) ? -p[k] : p[k];
        c[8] += (k & 1) ? -p[k] : p[k];
    }

    #pragma unroll
    for (int d = 1; d < 64; d <<= 1) {
        #pragma unroll
        for (int w = 0; w < 9; ++w)
            c[w] += __shfl_xor(c[w], d, 64);
    }

    float v = c[0];
    #pragma unroll
    for (int w = 1; w < 9; ++w)
        v = (lane == w) ? c[w] : v;
    if (lane < 9)
        out[b * 9 + lane] = v;
}

extern "C" void kernel_launch(void* const* d_in, const int* in_sizes, int n_in,
                              void* d_out, int out_size, void* d_ws, size_t ws_size,
                              hipStream_t stream) {
    const float* x  = (const float*)d_in[0];   // (32768, 9) fp32
    const float* wt = (const float*)d_in[1];   // (3, 9, 3) fp32
    float* out = (float*)d_out;                // (32768, 9) fp32
    const int batch = in_sizes[0] / 9;

    hipLaunchKernelGGL(qsim_kernel, dim3((batch + 3) / 4), dim3(256), 0, stream,
                       x, wt, out, batch);
}

// Round 3
// 137.017 us; speedup vs baseline: 1.7311x; 1.1757x over previous
//
#include <hip/hip_runtime.h>

// ---------------------------------------------------------------------------
// 9-qubit batched state-vector simulator, v3 (Euler-angle restructure).
// Each rotation M = Rz(omega)*Ry(theta)*Rz(phi):
//   - layer-1 Dphi folded into init product state (tensor phases)
//   - interior boundaries: one merged 512-entry phase table per boundary,
//     D(j) = Dom_l(j)*Dphi_{l+1}(P_l(j)), built once per block in LDS
//   - layer-3 Dom dropped at |psi|^2; P_3 folded into epilogue sign masks
// Gates are now REAL Ry (8 FMA/pair vs 16). 8 LDS round-trips (vs 9), all
// conflict-free via sigma(i)=i^(i>>4) swizzle (rank-4 bank-pair maps).
// ---------------------------------------------------------------------------

constexpr int pf(int l, int i) {        // forward CNOT-ring basis map, layer l
    const int r = l + 1; int j = i;
    for (int c = 0; c < 9; ++c) {
        const int bit = (j >> (8 - c)) & 1;
        const int t = (c + r) % 9;
        j ^= bit << (8 - t);
    }
    return j;
}
constexpr int sg(int i) { return i ^ (i >> 4); }   // LDS anti-conflict swizzle

// input-bit masks: bit p of P_bd(j) = parity(j & PM[bd][p])
struct PMask { int m[2][9]; };
constexpr PMask make_pmask() {
    PMask pm{};
    for (int bd = 0; bd < 2; ++bd)
        for (int q = 0; q < 9; ++q) {
            const int img = pf(bd, 1 << q);
            for (int p = 0; p < 9; ++p)
                if ((img >> p) & 1) pm.m[bd][p] |= 1 << q;
        }
    return pm;
}
constexpr PMask PM = make_pmask();

struct T3Tab { int laneBase[2][6]; int regPart[2][8]; };
constexpr T3Tab make_t3() {
    T3Tab t{};
    for (int l = 0; l < 2; ++l) {
        for (int b = 0; b < 6; ++b) t.laneBase[l][b] = sg(pf(l, 1 << b));
        for (int g = 0; g < 8; ++g) t.regPart [l][g] = sg(pf(l, g << 6));
    }
    return t;
}
constexpr T3Tab T3T = make_t3();

constexpr int sgk3(int k) { return (k << 3) ^ (k >> 1); }   // sg(k<<3)
constexpr int sgk6(int k) { return (k << 6) ^ (k << 2); }   // sg(k<<6)

#define PI_F 3.14159265358979323846f

// real Ry gate: new0 = c*a0 - s*a1 ; new1 = s*a0 + c*a1  (re & im)
#define APPLY_GATE(gidx, KB)                                                  \
    {                                                                         \
        const float2 g = GM[(gidx)];                                          \
        _Pragma("unroll")                                                     \
        for (int k0 = 0; k0 < 8; ++k0) if (!(k0 & (KB))) {                    \
            const int k1 = k0 | (KB);                                         \
            const float a0r = re[k0], a0i = im[k0];                           \
            const float a1r = re[k1], a1i = im[k1];                           \
            re[k0] = g.x * a0r - g.y * a1r;                                   \
            im[k0] = g.x * a0i - g.y * a1i;                                   \
            re[k1] = g.y * a0r + g.x * a1r;                                   \
            im[k1] = g.y * a0i + g.x * a1i;                                   \
        }                                                                     \
    }

__global__ __launch_bounds__(256) void qsim_kernel(
        const float* __restrict__ x,       // (batch, 9)
        const float* __restrict__ wt,      // (3, 9, 3)
        float* __restrict__ out,           // (batch, 9)
        int batch) {
    __shared__ float2 st[4][512];          // per-wave staging (16 KiB)
    __shared__ float2 diag[2][512];        // boundary phase tables (8 KiB)
    __shared__ float2 GM[27];              // gate (cos, sin), shared

    const int tid  = threadIdx.x;
    const int wv   = tid >> 6;
    const int lane = tid & 63;
    const int b    = blockIdx.x * 4 + wv;

    // ---- boundary phase tables: whole block builds 1024 entries ----
    #pragma unroll
    for (int bd = 0; bd < 2; ++bd) {
        #pragma unroll
        for (int h = 0; h < 2; ++h) {
            const int j = tid + 256 * h;               // 0..511
            float alpha = 0.0f;
            #pragma unroll
            for (int p = 0; p < 9; ++p) {
                const int w = 8 - p;
                const float om = wt[(bd * 9 + w) * 3 + 2];        // omega, layer bd
                const float ph = wt[((bd + 1) * 9 + w) * 3 + 0];  // phi, layer bd+1
                alpha += ((j >> p) & 1) ? 0.5f * om : -0.5f * om;
                alpha += (__popc(j & PM.m[bd][p]) & 1) ? 0.5f * ph : -0.5f * ph;
            }
            float sn, cs; __sincosf(alpha, &sn, &cs);
            diag[bd][j] = make_float2(cs, sn);
        }
    }

    // ---- gate (cos, sin): threads 0..26 build, shared across waves ----
    if (tid < 27) {
        float s, c; __sincosf(0.5f * wt[tid * 3 + 1], &s, &c);
        GM[tid] = make_float2(c, s);
    }
    __syncthreads();

    if (b >= batch) return;

    float2* __restrict__ S = st[wv];

    // ---- init: product state with layer-1 Dphi folded in ----
    // per-qubit factor: bit=0 -> cos(x/2)*e^{-i phi/2}; bit=1 -> sin(x/2)*e^{i(phi/2 - pi/2)}
    float cx[9], sx[9];
    #pragma unroll
    for (int w = 0; w < 9; ++w)
        __sincosf(0.5f * x[b * 9 + w], &sx[w], &cx[w]);

    float P = 1.0f, Alane = 0.0f;
    #pragma unroll
    for (int w = 0; w < 6; ++w) {
        const bool hi = (lane >> (5 - w)) & 1;
        const float phi = wt[w * 3 + 0];
        P *= hi ? sx[w] : cx[w];
        Alane += hi ? (0.5f * phi - 0.5f * PI_F) : (-0.5f * phi);
    }
    float mk[8], ak[8];
    #pragma unroll
    for (int k = 0; k < 8; ++k) {
        mk[k] = ((k & 4) ? sx[6] : cx[6]) * ((k & 2) ? sx[7] : cx[7])
              * ((k & 1) ? sx[8] : cx[8]);
        float a = 0.0f;
        a += (k & 4) ? (0.5f * wt[6 * 3] - 0.5f * PI_F) : (-0.5f * wt[6 * 3]);
        a += (k & 2) ? (0.5f * wt[7 * 3] - 0.5f * PI_F) : (-0.5f * wt[7 * 3]);
        a += (k & 1) ? (0.5f * wt[8 * 3] - 0.5f * PI_F) : (-0.5f * wt[8 * 3]);
        ak[k] = a;
    }
    float re[8], im[8];
    #pragma unroll
    for (int k = 0; k < 8; ++k) {
        const float m = P * mk[k];
        float sn, cs; __sincosf(Alane + ak[k], &sn, &cs);
        re[k] = m * cs; im[k] = m * sn;
    }

    // ---- swizzled address bases ----
    const int baseA = (lane << 3) ^ (lane >> 1);            // sg(L<<3)
    const int hB    = ((lane & 0x38) << 3) | (lane & 7);
    const int baseB = hB ^ (hB >> 4);
    const int baseC = lane ^ (lane >> 4);
    int t3b[2];
    #pragma unroll
    for (int l = 0; l < 2; ++l) {
        int v = 0;
        #pragma unroll
        for (int bb = 0; bb < 6; ++bb)
            v ^= ((lane >> bb) & 1) ? T3T.laneBase[l][bb] : 0;
        t3b[l] = v;
    }

    // ---- 3 layers of 9 real Ry gates, swizzled LDS layout cycling ----
    #pragma unroll
    for (int l = 0; l < 3; ++l) {
        APPLY_GATE(l * 9 + 6, 4);   // layout A: reg bits = qubits 6,7,8
        APPLY_GATE(l * 9 + 7, 2);
        APPLY_GATE(l * 9 + 8, 1);

        #pragma unroll
        for (int k = 0; k < 8; ++k) S[baseA ^ k] = make_float2(re[k], im[k]);
        #pragma unroll
        for (int k = 0; k < 8; ++k) {
            const float2 v = S[baseB ^ sgk3(k)];
            re[k] = v.x; im[k] = v.y;
        }

        APPLY_GATE(l * 9 + 3, 4);   // layout B: reg bits = qubits 3,4,5
        APPLY_GATE(l * 9 + 4, 2);
        APPLY_GATE(l * 9 + 5, 1);

        #pragma unroll
        for (int k = 0; k < 8; ++k) S[baseB ^ sgk3(k)] = make_float2(re[k], im[k]);
        #pragma unroll
        for (int k = 0; k < 8; ++k) {
            const float2 v = S[baseC ^ sgk6(k)];
            re[k] = v.x; im[k] = v.y;
        }

        APPLY_GATE(l * 9 + 0, 4);   // layout C: reg bits = qubits 0,1,2
        APPLY_GATE(l * 9 + 1, 2);
        APPLY_GATE(l * 9 + 2, 1);

        if (l < 2) {
            // merged boundary diagonal (pre-perm basis j = k<<6 | lane)
            #pragma unroll
            for (int k = 0; k < 8; ++k) {
                const float2 d = diag[l][(k << 6) | lane];
                const float nr = re[k] * d.x - im[k] * d.y;
                const float ni = re[k] * d.y + im[k] * d.x;
                re[k] = nr; im[k] = ni;
            }
            // T3: C -> A with the CNOT-ring permutation folded in
            #pragma unroll
            for (int k = 0; k < 8; ++k)
                S[t3b[l] ^ T3T.regPart[l][k]] = make_float2(re[k], im[k]);
            #pragma unroll
            for (int k = 0; k < 8; ++k) {
                const float2 v = S[baseA ^ k];
                re[k] = v.x; im[k] = v.y;
            }
        }
    }

    // ---- epilogue in layout C with P_3 folded into sign masks ----
    // q0:(L2^L5,S) q1:(L1^L4,S) q2:(L0^L3,S) q3:(L5,U4) q4:(L4,U2) q5:(L3,U1)
    // q6:(L2^L5,U4) q7:(L1^L4,U2) q8:(L0^L3,U1)   [k bit: 4<->j8, 2<->j7, 1<->j6]
    float p[8];
    #pragma unroll
    for (int k = 0; k < 8; ++k) p[k] = re[k] * re[k] + im[k] * im[k];

    float Ssum = 0.0f, U4 = 0.0f, U2 = 0.0f, U1 = 0.0f;
    #pragma unroll
    for (int k = 0; k < 8; ++k) {
        Ssum += p[k];
        U4 += (k & 4) ? -p[k] : p[k];
        U2 += (k & 2) ? -p[k] : p[k];
        U1 += (k & 1) ? -p[k] : p[k];
    }

    const bool l25 = ((lane >> 2) ^ (lane >> 5)) & 1;
    const bool l14 = ((lane >> 1) ^ (lane >> 4)) & 1;
    const bool l03 = ( lane       ^ (lane >> 3)) & 1;
    const bool l5  = (lane >> 5) & 1;
    const bool l4  = (lane >> 4) & 1;
    const bool l3  = (lane >> 3) & 1;

    float c[9];
    c[0] = l25 ? -Ssum : Ssum;
    c[1] = l14 ? -Ssum : Ssum;
    c[2] = l03 ? -Ssum : Ssum;
    c[3] = l5  ? -U4   : U4;
    c[4] = l4  ? -U2   : U2;
    c[5] = l3  ? -U1   : U1;
    c[6] = l25 ? -U4   : U4;
    c[7] = l14 ? -U2   : U2;
    c[8] = l03 ? -U1   : U1;

    #pragma unroll
    for (int d = 1; d < 64; d <<= 1) {
        #pragma unroll
        for (int w = 0; w < 9; ++w)
            c[w] += __shfl_xor(c[w], d, 64);
    }

    float v = c[0];
    #pragma unroll
    for (int w = 1; w < 9; ++w)
        v = (lane == w) ? c[w] : v;
    if (lane < 9)
        out[b * 9 + lane] = v;
}

extern "C" void kernel_launch(void* const* d_in, const int* in_sizes, int n_in,
                              void* d_out, int out_size, void* d_ws, size_t ws_size,
                              hipStream_t stream) {
    const float* x  = (const float*)d_in[0];   // (32768, 9) fp32
    const float* wt = (const float*)d_in[1];   // (3, 9, 3) fp32
    float* out = (float*)d_out;                // (32768, 9) fp32
    const int batch = in_sizes[0] / 9;

    hipLaunchKernelGGL(qsim_kernel, dim3((batch + 3) / 4), dim3(256), 0, stream,
                       x, wt, out, batch);
}

// Round 4
// 115.297 us; speedup vs baseline: 2.0572x; 1.1884x over previous
//
#include <hip/hip_runtime.h>

// ---------------------------------------------------------------------------
// 9-qubit batched state-vector simulator, v4.
//  - all batch-independent tables (gate cos/sin, boundary phase diagonals,
//    init-state phase) hoisted to a one-block pre-kernel -> d_ws
//  - amplitudes held as packed float2 (ext_vector_type) so real-Ry gates
//    become v_pk_fma_f32 (re/im share coefficients)
//  - LDS holds ONLY the per-wave staging buffer (16 KB/block); diagonals and
//    init-phase read from global (L1-resident), no __syncthreads anywhere
// ---------------------------------------------------------------------------

typedef float v2f __attribute__((ext_vector_type(2)));

constexpr int pf(int l, int i) {        // forward CNOT-ring basis map, layer l
    const int r = l + 1; int j = i;
    for (int c = 0; c < 9; ++c) {
        const int bit = (j >> (8 - c)) & 1;
        const int t = (c + r) % 9;
        j ^= bit << (8 - t);
    }
    return j;
}
constexpr int sg(int i) { return i ^ (i >> 4); }   // LDS anti-conflict swizzle

// bit p of P_bd(j) = parity(j & PM.m[bd][p])
struct PMask { int m[2][9]; };
constexpr PMask make_pmask() {
    PMask pm{};
    for (int bd = 0; bd < 2; ++bd)
        for (int q = 0; q < 9; ++q) {
            const int img = pf(bd, 1 << q);
            for (int p = 0; p < 9; ++p)
                if ((img >> p) & 1) pm.m[bd][p] |= 1 << q;
        }
    return pm;
}
constexpr PMask PM = make_pmask();

struct T3Tab { int laneBase[2][6]; int regPart[2][8]; };
constexpr T3Tab make_t3() {
    T3Tab t{};
    for (int l = 0; l < 2; ++l) {
        for (int b = 0; b < 6; ++b) t.laneBase[l][b] = sg(pf(l, 1 << b));
        for (int g = 0; g < 8; ++g) t.regPart [l][g] = sg(pf(l, g << 6));
    }
    return t;
}
constexpr T3Tab T3T = make_t3();

constexpr int sgk3(int k) { return (k << 3) ^ (k >> 1); }   // sg(k<<3)
constexpr int sgk6(int k) { return (k << 6) ^ (k << 2); }   // sg(k<<6)

#define PI_F 3.14159265358979323846f

// ws layout in v2f units:
//   [0..27)      GM   : (cos th/2, sin th/2) per gate (l*9+w)
//   [32..544)    diag0: merged boundary phase, layers 1->2
//   [544..1056)  diag1: merged boundary phase, layers 2->3
//   [1056..1568) phase: init-state phase e^{i sum_w (bit? phi/2-pi/2 : -phi/2)}
__global__ __launch_bounds__(512) void qtab_kernel(
        const float* __restrict__ wt, v2f* __restrict__ ws) {
    const int j = threadIdx.x;             // 0..511
    if (j < 27) {
        float s, c; __sincosf(0.5f * wt[j * 3 + 1], &s, &c);
        ws[j] = (v2f){c, s};
    }
    #pragma unroll
    for (int bd = 0; bd < 2; ++bd) {
        float alpha = 0.0f;
        #pragma unroll
        for (int p = 0; p < 9; ++p) {
            const int w = 8 - p;
            const float om = wt[(bd * 9 + w) * 3 + 2];        // omega, layer bd
            const float ph = wt[((bd + 1) * 9 + w) * 3 + 0];  // phi, layer bd+1
            alpha += ((j >> p) & 1) ? 0.5f * om : -0.5f * om;
            alpha += (__popc(j & PM.m[bd][p]) & 1) ? 0.5f * ph : -0.5f * ph;
        }
        float sn, cs; __sincosf(alpha, &sn, &cs);
        ws[32 + bd * 512 + j] = (v2f){cs, sn};
    }
    {
        float a = 0.0f;
        #pragma unroll
        for (int p = 0; p < 9; ++p) {
            const int w = 8 - p;
            const float phi = wt[w * 3 + 0];
            a += ((j >> p) & 1) ? (0.5f * phi - 0.5f * PI_F) : (-0.5f * phi);
        }
        float sn, cs; __sincosf(a, &sn, &cs);
        ws[1056 + j] = (v2f){cs, sn};
    }
}

// real Ry on packed (re,im): a0' = c*a0 - s*a1 ; a1' = s*a0 + c*a1
#define APPLY_GATE(gidx, KB)                                                  \
    {                                                                         \
        const v2f g  = GC[(gidx)];                                            \
        const v2f gc = (v2f){g.x, g.x};                                       \
        const v2f gs = (v2f){g.y, g.y};                                       \
        _Pragma("unroll")                                                     \
        for (int k0 = 0; k0 < 8; ++k0) if (!(k0 & (KB))) {                    \
            const int k1 = k0 | (KB);                                         \
            const v2f a0 = a[k0], a1 = a[k1];                                 \
            a[k0] = a0 * gc - a1 * gs;                                        \
            a[k1] = a0 * gs + a1 * gc;                                        \
        }                                                                     \
    }

__global__ __launch_bounds__(256) void qsim_kernel(
        const float* __restrict__ x,       // (batch, 9)
        const v2f*   __restrict__ tab,     // ws tables
        float* __restrict__ out,           // (batch, 9)
        int batch) {
    __shared__ v2f st[4][512];             // per-wave staging (16 KiB)

    const int tid  = threadIdx.x;
    const int wv   = tid >> 6;
    const int lane = tid & 63;
    const int b    = blockIdx.x * 4 + wv;
    if (b >= batch) return;

    v2f* __restrict__ S = st[wv];
    const v2f* __restrict__ GC = tab;          // 27 gate (c,s)
    const v2f* __restrict__ D0 = tab + 32;     // 512
    const v2f* __restrict__ D1 = tab + 544;    // 512
    const v2f* __restrict__ PH = tab + 1056;   // 512

    // ---- init: magnitudes from x, phase from precomputed table ----
    float cx[9], sx[9];
    #pragma unroll
    for (int w = 0; w < 9; ++w)
        __sincosf(0.5f * x[b * 9 + w], &sx[w], &cx[w]);

    float P = 1.0f;
    #pragma unroll
    for (int w = 0; w < 6; ++w)
        P *= ((lane >> (5 - w)) & 1) ? sx[w] : cx[w];

    v2f a[8];
    #pragma unroll
    for (int k = 0; k < 8; ++k) {
        const float m = P * ((k & 4) ? sx[6] : cx[6])
                          * ((k & 2) ? sx[7] : cx[7])
                          * ((k & 1) ? sx[8] : cx[8]);
        a[k] = PH[(lane << 3) | k] * m;
    }

    // ---- swizzled address bases ----
    const int baseA = (lane << 3) ^ (lane >> 1);            // sg(L<<3)
    const int hB    = ((lane & 0x38) << 3) | (lane & 7);
    const int baseB = hB ^ (hB >> 4);
    const int baseC = lane ^ (lane >> 4);
    int t3b[2];
    #pragma unroll
    for (int l = 0; l < 2; ++l) {
        int v = 0;
        #pragma unroll
        for (int bb = 0; bb < 6; ++bb)
            v ^= ((lane >> bb) & 1) ? T3T.laneBase[l][bb] : 0;
        t3b[l] = v;
    }

    // ---- 3 layers of 9 real Ry gates, swizzled LDS layout cycling ----
    #pragma unroll
    for (int l = 0; l < 3; ++l) {
        APPLY_GATE(l * 9 + 6, 4);   // layout A: reg bits = qubits 6,7,8
        APPLY_GATE(l * 9 + 7, 2);
        APPLY_GATE(l * 9 + 8, 1);

        #pragma unroll
        for (int k = 0; k < 8; ++k) S[baseA ^ k] = a[k];
        #pragma unroll
        for (int k = 0; k < 8; ++k) a[k] = S[baseB ^ sgk3(k)];

        APPLY_GATE(l * 9 + 3, 4);   // layout B: reg bits = qubits 3,4,5
        APPLY_GATE(l * 9 + 4, 2);
        APPLY_GATE(l * 9 + 5, 1);

        #pragma unroll
        for (int k = 0; k < 8; ++k) S[baseB ^ sgk3(k)] = a[k];
        #pragma unroll
        for (int k = 0; k < 8; ++k) a[k] = S[baseC ^ sgk6(k)];

        APPLY_GATE(l * 9 + 0, 4);   // layout C: reg bits = qubits 0,1,2
        APPLY_GATE(l * 9 + 1, 2);
        APPLY_GATE(l * 9 + 2, 1);

        if (l < 2) {
            // merged boundary diagonal (pre-perm basis j = k<<6 | lane), global
            const v2f* __restrict__ D = (l == 0) ? D0 : D1;
            #pragma unroll
            for (int k = 0; k < 8; ++k) {
                const v2f d = D[(k << 6) | lane];
                const v2f av = a[k];
                a[k] = (v2f){av.x * d.x - av.y * d.y,
                             av.x * d.y + av.y * d.x};
            }
            // T3: C -> A with the CNOT-ring permutation folded in
            #pragma unroll
            for (int k = 0; k < 8; ++k)
                S[t3b[l] ^ T3T.regPart[l][k]] = a[k];
            #pragma unroll
            for (int k = 0; k < 8; ++k) a[k] = S[baseA ^ k];
        }
    }

    // ---- epilogue in layout C with P_3 folded into sign masks ----
    float p[8];
    #pragma unroll
    for (int k = 0; k < 8; ++k) {
        const v2f q = a[k] * a[k];
        p[k] = q.x + q.y;
    }

    float Ssum = 0.0f, U4 = 0.0f, U2 = 0.0f, U1 = 0.0f;
    #pragma unroll
    for (int k = 0; k < 8; ++k) {
        Ssum += p[k];
        U4 += (k & 4) ? -p[k] : p[k];
        U2 += (k & 2) ? -p[k] : p[k];
        U1 += (k & 1) ? -p[k] : p[k];
    }

    const bool l25 = ((lane >> 2) ^ (lane >> 5)) & 1;
    const bool l14 = ((lane >> 1) ^ (lane >> 4)) & 1;
    const bool l03 = ( lane       ^ (lane >> 3)) & 1;
    const bool l5  = (lane >> 5) & 1;
    const bool l4  = (lane >> 4) & 1;
    const bool l3  = (lane >> 3) & 1;

    float c[9];
    c[0] = l25 ? -Ssum : Ssum;
    c[1] = l14 ? -Ssum : Ssum;
    c[2] = l03 ? -Ssum : Ssum;
    c[3] = l5  ? -U4   : U4;
    c[4] = l4  ? -U2   : U2;
    c[5] = l3  ? -U1   : U1;
    c[6] = l25 ? -U4   : U4;
    c[7] = l14 ? -U2   : U2;
    c[8] = l03 ? -U1   : U1;

    #pragma unroll
    for (int d = 1; d < 64; d <<= 1) {
        #pragma unroll
        for (int w = 0; w < 9; ++w)
            c[w] += __shfl_xor(c[w], d, 64);
    }

    float v = c[0];
    #pragma unroll
    for (int w = 1; w < 9; ++w)
        v = (lane == w) ? c[w] : v;
    if (lane < 9)
        out[b * 9 + lane] = v;
}

extern "C" void kernel_launch(void* const* d_in, const int* in_sizes, int n_in,
                              void* d_out, int out_size, void* d_ws, size_t ws_size,
                              hipStream_t stream) {
    const float* x  = (const float*)d_in[0];   // (32768, 9) fp32
    const float* wt = (const float*)d_in[1];   // (3, 9, 3) fp32
    float* out = (float*)d_out;                // (32768, 9) fp32
    const int batch = in_sizes[0] / 9;
    v2f* ws = (v2f*)d_ws;                      // 1568 * 8 B = 12.5 KB used

    hipLaunchKernelGGL(qtab_kernel, dim3(1), dim3(512), 0, stream, wt, ws);
    hipLaunchKernelGGL(qsim_kernel, dim3((batch + 3) / 4), dim3(256), 0, stream,
                       x, (const v2f*)ws, out, batch);
}